// Round 1
// baseline (279.101 us; speedup 1.0000x reference)
//
#include <hip/hip_runtime.h>
#include <math.h>

#define Hd 192
#define Wd 640
#define HWp (Hd * Wd)
#define NCLS 3
#define KTOP 50
#define NB 32
#define CAND_CAP 2048
#define PI_F 3.14159265358979f

// ---------------------------------------------------------------------------
// Kernel A: per-(b,c) plane fused NMS + exact top-50 selection.
// One block per plane (96 blocks, 1024 threads).
// ---------------------------------------------------------------------------

// Iterate all pixels of the plane in 8-pixel horizontal strips, computing the
// 3x3 -inf-padded max-pool on the fly; invoke f(bits, index) for every peak
// (pixel equal to its 3x3 window max). ~3.75 loads/pixel via float4 + edges.
template <typename F>
__device__ inline void for_each_peak(const float* __restrict__ p, int tid, F f) {
  for (int chunk = tid; chunk < (HWp / 8); chunk += 1024) {
    int y = chunk / (Wd / 8);
    int x0 = (chunk - y * (Wd / 8)) * 8;
    float r[3][10];
#pragma unroll
    for (int dy = 0; dy < 3; ++dy) {
      int yy = y + dy - 1;
      if (yy < 0 || yy >= Hd) {
#pragma unroll
        for (int i = 0; i < 10; ++i) r[dy][i] = -INFINITY;
        continue;
      }
      const float* rp = p + yy * Wd + x0;
      float4 a = *(const float4*)rp;
      float4 bq = *(const float4*)(rp + 4);
      r[dy][1] = a.x; r[dy][2] = a.y; r[dy][3] = a.z; r[dy][4] = a.w;
      r[dy][5] = bq.x; r[dy][6] = bq.y; r[dy][7] = bq.z; r[dy][8] = bq.w;
      r[dy][0] = (x0 > 0) ? rp[-1] : -INFINITY;
      r[dy][9] = (x0 + 8 < Wd) ? rp[8] : -INFINITY;
    }
    float vm[10];
#pragma unroll
    for (int i = 0; i < 10; ++i)
      vm[i] = fmaxf(fmaxf(r[0][i], r[1][i]), r[2][i]);
#pragma unroll
    for (int i = 0; i < 8; ++i) {
      float v = r[1][i + 1];
      float hm = fmaxf(fmaxf(vm[i], vm[i + 1]), vm[i + 2]);
      if (v == hm) f(__float_as_uint(v), y * Wd + x0 + i);
    }
  }
}

__global__ __launch_bounds__(1024) void topk_plane_kernel(
    const float* __restrict__ heat,
    float* __restrict__ out_scores,  // [96][50]
    int* __restrict__ out_inds) {    // [96][50]
  const int plane = blockIdx.x;
  const float* p = heat + (size_t)plane * HWp;
  const int tid = threadIdx.x;

  __shared__ unsigned int cand_bits[CAND_CAP];
  __shared__ int cand_idx[CAND_CAP];
  __shared__ int cand_cnt;
  __shared__ unsigned int hist[1024];
  __shared__ int s_B, s_above, s_T;

  if (tid == 0) cand_cnt = 0;
  __syncthreads();

  // Pass 1: collect peak candidates with value >= 0.995 (bit-pattern compare
  // valid for non-negative floats). Top-50 of this data is always >> 0.995.
  const unsigned int THRESH_BITS = __float_as_uint(0.995f);
  for_each_peak(p, tid, [&](unsigned int bits, int idx) {
    if (bits >= THRESH_BITS) {
      int slot = atomicAdd(&cand_cnt, 1);
      if (slot < CAND_CAP) { cand_bits[slot] = bits; cand_idx[slot] = idx; }
    }
  });
  __syncthreads();
  int M = cand_cnt;

  // Exact fallback (radix-select over float bits) — never triggers on this
  // data, kept for robustness.
  if (M < KTOP || M > CAND_CAP) {
    for (int i = tid; i < 1024; i += 1024) hist[i] = 0;
    __syncthreads();
    for_each_peak(p, tid, [&](unsigned int bits, int idx) {
      atomicAdd(&hist[bits >> 20], 1u);
    });
    __syncthreads();
    if (tid == 0) {
      int acc = 0, Bs = -1;
      for (int bkt = 1023; bkt >= 0; --bkt) {
        int c = (int)hist[bkt];
        if (acc + c >= KTOP) { Bs = bkt; s_above = acc; break; }
        acc += c;
      }
      s_B = Bs;
      if (Bs < 0) s_above = acc;
    }
    __syncthreads();
    int Bs = s_B;
    unsigned int T;
    if (Bs < 0) {
      T = 0;  // fewer than 50 peaks total: take them all
    } else {
      for (int i = tid; i < 1024; i += 1024) hist[i] = 0;
      __syncthreads();
      for_each_peak(p, tid, [&](unsigned int bits, int idx) {
        if ((int)(bits >> 20) == Bs) atomicAdd(&hist[(bits >> 10) & 1023], 1u);
      });
      __syncthreads();
      if (tid == 0) {
        int acc = s_above, Ss = 0;
        for (int sb = 1023; sb >= 0; --sb) {
          int c = (int)hist[sb];
          if (acc + c >= KTOP) { Ss = sb; break; }
          acc += c;
        }
        s_T = (Bs << 20) | (Ss << 10);
      }
      __syncthreads();
      T = (unsigned int)s_T;
    }
    if (tid == 0) cand_cnt = 0;
    __syncthreads();
    for_each_peak(p, tid, [&](unsigned int bits, int idx) {
      if (bits >= T) {
        int slot = atomicAdd(&cand_cnt, 1);
        if (slot < CAND_CAP) { cand_bits[slot] = bits; cand_idx[slot] = idx; }
      }
    });
    __syncthreads();
    M = cand_cnt < CAND_CAP ? cand_cnt : CAND_CAP;
  }

  // Rank candidates by (value desc, index asc) — reproduces jax.lax.top_k's
  // stable tie-break exactly. Excluded elements are strictly smaller.
  for (int i = tid; i < M; i += 1024) {
    unsigned int vb = cand_bits[i];
    int vi = cand_idx[i];
    int rank = 0;
    for (int j = 0; j < M; ++j) {
      unsigned int wb = cand_bits[j];
      rank += (wb > vb) || (wb == vb && cand_idx[j] < vi);
    }
    if (rank < KTOP) {
      out_scores[plane * KTOP + rank] = __uint_as_float(vb);
      out_inds[plane * KTOP + rank] = vi;
    }
  }
  // Pathological (<50 peaks): fill remaining slots (score 0 rows get zeroed
  // in the final output anyway since 0 <= DET_THRESHOLD).
  for (int s = M + tid; s < KTOP; s += 1024) {
    out_scores[plane * KTOP + s] = 0.0f;
    out_inds[plane * KTOP + s] = 0;
  }
}

// ---------------------------------------------------------------------------
// Kernel B: per-batch top-50 over the 3*50 class scores + full 3D decode.
// One block per batch (32 blocks, 192 threads).
// ---------------------------------------------------------------------------

__device__ inline void inv3(const float* m, float* o) {
  float a = m[0], b = m[1], c = m[2];
  float d = m[3], e = m[4], f = m[5];
  float g = m[6], h = m[7], i = m[8];
  float A = e * i - f * h;
  float B = -(d * i - f * g);
  float C = d * h - e * g;
  float det = a * A + b * B + c * C;
  float id = 1.0f / det;
  o[0] = A * id;            o[1] = -(b * i - c * h) * id; o[2] = (b * f - c * e) * id;
  o[3] = B * id;            o[4] = (a * i - c * g) * id;  o[5] = -(a * f - c * d) * id;
  o[6] = C * id;            o[7] = -(a * h - b * g) * id; o[8] = (a * e - b * d) * id;
}

__device__ inline float wrap_pi(float a) {
  if (a > PI_F) return a - 2.0f * PI_F;
  if (a < -PI_F) return a + 2.0f * PI_F;
  return a;
}

__constant__ float DIM_REF_C[9] = {3.88f, 1.63f, 1.53f,
                                   0.84f, 1.76f, 0.66f,
                                   1.78f, 1.52f, 1.78f};

__global__ __launch_bounds__(192) void detect_kernel(
    const float* __restrict__ regr,      // [B][8][HWp]
    const float* __restrict__ trans_mat, // [B][3][3]
    const float* __restrict__ K_mat,     // [B][3][3]
    const float* __restrict__ img_size,  // [B][2]
    const float* __restrict__ ws_scores, // [96][50]
    const int* __restrict__ ws_inds,     // [96][50]
    float* __restrict__ out) {           // [B*50][14]
  const int b = blockIdx.x;
  const int tid = threadIdx.x;
  __shared__ float sc[NCLS * KTOP];
  __shared__ int pi[NCLS * KTOP];
  __shared__ int sel[KTOP];

  if (tid < NCLS * KTOP) {
    int c = tid / KTOP, k = tid - c * KTOP;
    sc[tid] = ws_scores[(b * NCLS + c) * KTOP + k];
    pi[tid] = ws_inds[(b * NCLS + c) * KTOP + k];
  }
  __syncthreads();

  if (tid < NCLS * KTOP) {
    float v = sc[tid];
    int rank = 0;
    for (int j = 0; j < NCLS * KTOP; ++j) {
      float w = sc[j];
      rank += (w > v) || (w == v && j < tid);
    }
    if (rank < KTOP) sel[rank] = tid;
  }
  __syncthreads();

  if (tid < KTOP) {
    int i = sel[tid];
    int cls = i / KTOP;
    float score = sc[i];
    int ind = pi[i];
    float ys = (float)(ind / Wd);
    float xs = (float)(ind - (ind / Wd) * Wd);

    // gather 8 regression channels at this point
    const float* rb = regr + (size_t)b * 8 * HWp + ind;
    float r0 = rb[0 * HWp], r1 = rb[1 * HWp], r2 = rb[2 * HWp], r3 = rb[3 * HWp];
    float r4 = rb[4 * HWp], r5 = rb[5 * HWp], r6 = rb[6 * HWp], r7 = rb[7 * HWp];

    float tm[9], km[9], tmi[9], kmi[9];
#pragma unroll
    for (int q = 0; q < 9; ++q) { tm[q] = trans_mat[b * 9 + q]; km[q] = K_mat[b * 9 + q]; }
    inv3(tm, tmi);
    inv3(km, kmi);

    // project point back to image coords
    float px = xs + r1, py = ys + r2;
    float gx = tmi[0] * px + tmi[1] * py + tmi[2];
    float gy = tmi[3] * px + tmi[4] * py + tmi[5];
    float gz = tmi[6] * px + tmi[7] * py + tmi[8];
    float depth = r0 * 16.32f + 28.01f;
    float qx = gx * depth, qy = gy * depth, qz = gz * depth;
    float lx = kmi[0] * qx + kmi[1] * qy + kmi[2] * qz;
    float ly = kmi[3] * qx + kmi[4] * qy + kmi[5] * qz;
    float lz = kmi[6] * qx + kmi[7] * qy + kmi[8] * qz;

    float d0 = expf(r3) * DIM_REF_C[cls * 3 + 0];
    float d1 = expf(r4) * DIM_REF_C[cls * 3 + 1];
    float d2 = expf(r5) * DIM_REF_C[cls * 3 + 2];
    ly += d1 * 0.5f;

    float ray = atanf(lx / (lz + 1e-7f));
    float alpha = atanf(r6 / (r7 + 1e-7f));
    alpha += (r7 >= 0.0f) ? -PI_F * 0.5f : PI_F * 0.5f;
    float roty = wrap_pi(alpha + ray);
    alpha = wrap_pi(alpha);

    // 8 corners, rotate, translate, project with K, track min/max
    const float SX[8] = {-0.5f, 0.5f, 0.5f, 0.5f, 0.5f, -0.5f, -0.5f, -0.5f};
    const float SY[8] = {-1.0f, -1.0f, 0.0f, 0.0f, -1.0f, -1.0f, 0.0f, 0.0f};
    const float SZ[8] = {-0.5f, -0.5f, -0.5f, 0.5f, 0.5f, 0.5f, 0.5f, -0.5f};
    float cr = cosf(roty), sr = sinf(roty);
    float minx = INFINITY, maxx = -INFINITY, miny = INFINITY, maxy = -INFINITY;
#pragma unroll
    for (int j = 0; j < 8; ++j) {
      float ax = d0 * SX[j], ay = d1 * SY[j], az = d2 * SZ[j];
      float cx = cr * ax + sr * az + lx;
      float cy = ay + ly;
      float cz = -sr * ax + cr * az + lz;
      float ppx = km[0] * cx + km[1] * cy + km[2] * cz;
      float ppy = km[3] * cx + km[4] * cy + km[5] * cz;
      float ppz = km[6] * cx + km[7] * cy + km[8] * cz;
      float X = ppx / ppz, Y = ppy / ppz;
      minx = fminf(minx, X); maxx = fmaxf(maxx, X);
      miny = fminf(miny, Y); maxy = fmaxf(maxy, Y);
    }
    float Wi = img_size[b * 2 + 0], Hi = img_size[b * 2 + 1];
    float xmin = fminf(fmaxf(minx, 0.0f), Wi);
    float ymin = fminf(fmaxf(miny, 0.0f), Hi);
    float xmax = fminf(fmaxf(maxx, 0.0f), Wi);
    float ymax = fminf(fmaxf(maxy, 0.0f), Hi);

    float* o = out + (size_t)(b * KTOP + tid) * 14;
    if (score > 0.25f) {
      o[0] = (float)cls; o[1] = alpha;
      o[2] = xmin; o[3] = ymin; o[4] = xmax; o[5] = ymax;
      o[6] = d1; o[7] = d2; o[8] = d0;   // dims rolled by -1
      o[9] = lx; o[10] = ly; o[11] = lz;
      o[12] = roty; o[13] = score;
    } else {
#pragma unroll
      for (int q = 0; q < 14; ++q) o[q] = 0.0f;
    }
  }
}

// ---------------------------------------------------------------------------

extern "C" void kernel_launch(void* const* d_in, const int* in_sizes, int n_in,
                              void* d_out, int out_size, void* d_ws, size_t ws_size,
                              hipStream_t stream) {
  const float* heat = (const float*)d_in[0];       // [32,3,192,640]
  const float* regr = (const float*)d_in[1];       // [32,8,192,640]
  const float* tmat = (const float*)d_in[2];       // [32,3,3]
  const float* kmat = (const float*)d_in[3];       // [32,3,3]
  const float* isz = (const float*)d_in[4];        // [32,2]

  float* ws_scores = (float*)d_ws;                             // 96*50 floats
  int* ws_inds = (int*)((char*)d_ws + NB * NCLS * KTOP * sizeof(float));

  topk_plane_kernel<<<NB * NCLS, 1024, 0, stream>>>(heat, ws_scores, ws_inds);
  detect_kernel<<<NB, 192, 0, stream>>>(regr, tmat, kmat, isz, ws_scores, ws_inds,
                                        (float*)d_out);
}